// Round 7
// baseline (130.572 us; speedup 1.0000x reference)
//
#include <hip/hip_runtime.h>
#include <math.h>

#define B_      4
#define NH      8
#define HD      32
#define WINNUM  49
#define LWIN    3136
#define NTOK    3137
#define NPIX    12544     // B * 56 * 56
#define MROWS   12548     // NPIX + 4 cls rows
// 256^-0.5 * log2(e): scores land in exp2 domain
#define SCALE_L2E 0.09016844005556021f
#define SM_BIAS   4.0f    // fixed softmax bias (cancels in normalization)

typedef _Float16 half_t;
using half8 = __attribute__((ext_vector_type(8))) half_t;
using half4 = __attribute__((ext_vector_type(4))) half_t;
using f32x4 = __attribute__((ext_vector_type(4))) float;

__device__ __forceinline__ unsigned pack2(float a, float b) {
    auto h = __builtin_amdgcn_cvt_pkrtz(a, b);   // __fp16 ext_vector(2)
    return __builtin_bit_cast(unsigned, h);
}

// ---------------------------------------------------------------------------
// prep: xh = fp16([x;cls]) (12548,256); Wqkvt (768,256) and Wot (256,256)
// transposed fp16 (row = output col, k contiguous).
// ---------------------------------------------------------------------------
__global__ __launch_bounds__(256)
void prep(const float* __restrict__ x, const float* __restrict__ cls,
          const float* __restrict__ Wqkv, const float* __restrict__ Wo,
          half_t* __restrict__ xh, half_t* __restrict__ Wqkvt, half_t* __restrict__ Wot)
{
    const int idx = blockIdx.x * 256 + threadIdx.x;
    const int stride = gridDim.x * 256;
    for (int i = idx; i < MROWS * 256; i += stride) {
        int row = i >> 8, c = i & 255;
        float v = (row < NPIX) ? x[i] : cls[(row - NPIX) * 256 + c];
        xh[i] = (half_t)v;
    }
    for (int i = idx; i < 768 * 256; i += stride) {
        int n = i >> 8, k = i & 255;
        Wqkvt[i] = (half_t)Wqkv[k * 768 + n];
    }
    for (int i = idx; i < 256 * 256; i += stride) {
        int n = i >> 8, k = i & 255;
        Wot[i] = (half_t)Wo[k * 256 + n];
    }
}

// ---------------------------------------------------------------------------
// qkv_gemm: C = xh @ Wqkv + bqkv via fp16 MFMA, 128x128 tile, 4 waves.
// Reg-staged double buffer. Epilogue scatters q/k/v to attention layouts.
// ---------------------------------------------------------------------------
__global__ __launch_bounds__(256)
void qkv_gemm(const half_t* __restrict__ xh, const half_t* __restrict__ Bt,
              const float* __restrict__ bqkv,
              half_t* __restrict__ qh, half_t* __restrict__ kh,
              half_t* __restrict__ khcls, half_t* __restrict__ vh,
              half_t* __restrict__ vplain)
{
    __shared__ __align__(16) short As[2][128 * 40];
    __shared__ __align__(16) short Bs[2][128 * 40];
    const int m0 = blockIdx.y * 128, n0 = blockIdx.x * 128;
    const int tid = threadIdx.x;
    const int lane = tid & 63, wv = tid >> 6;
    const int wm = wv >> 1, wn = wv & 1;
    const int qi = lane & 15, g = lane >> 4;
    f32x4 acc[4][4] = {};

    int4 ra[2], rb[2];
    auto issue = [&](int k0) {
#pragma unroll
        for (int i = 0; i < 2; ++i) {
            int ch = tid + 256 * i;
            int row = ch >> 2, kc = (ch & 3) * 8;
            int m = m0 + row;
            ra[i] = (m < MROWS) ? *(const int4*)(xh + (size_t)m * 256 + k0 + kc)
                                : make_int4(0, 0, 0, 0);
            rb[i] = *(const int4*)(Bt + (size_t)(n0 + row) * 256 + k0 + kc);
        }
    };
    auto commit = [&](int bu) {
#pragma unroll
        for (int i = 0; i < 2; ++i) {
            int ch = tid + 256 * i;
            int row = ch >> 2, kc = (ch & 3) * 8;
            *(int4*)&As[bu][row * 40 + kc] = ra[i];
            *(int4*)&Bs[bu][row * 40 + kc] = rb[i];
        }
    };

    issue(0); commit(0);
    __syncthreads();
    int buf = 0;
    for (int s = 0; s < 8; ++s) {
        if (s < 7) issue((s + 1) * 32);
        half8 af[4], bf[4];
#pragma unroll
        for (int f = 0; f < 4; ++f) {
            af[f] = *(const half8*)&As[buf][(wm * 64 + f * 16 + qi) * 40 + g * 8];
            bf[f] = *(const half8*)&Bs[buf][(wn * 64 + f * 16 + qi) * 40 + g * 8];
        }
#pragma unroll
        for (int fm = 0; fm < 4; ++fm)
#pragma unroll
            for (int fn = 0; fn < 4; ++fn)
                acc[fm][fn] = __builtin_amdgcn_mfma_f32_16x16x32_f16(af[fm], bf[fn], acc[fm][fn], 0, 0, 0);
        if (s < 7) commit(buf ^ 1);
        __syncthreads();
        buf ^= 1;
    }

    const int part = n0 >> 8;
    int nhv[4], dv[4];
    float bq[4];
#pragma unroll
    for (int fn = 0; fn < 4; ++fn) {
        int n = n0 + wn * 64 + fn * 16 + qi;
        bq[fn] = bqkv[n];
        int c = n & 255;
        nhv[fn] = c >> 5; dv[fn] = c & 31;
    }
#pragma unroll
    for (int fm = 0; fm < 4; ++fm) {
#pragma unroll
        for (int r = 0; r < 4; ++r) {
            int m = m0 + wm * 64 + fm * 16 + g * 4 + r;
            if (m >= MROWS) continue;
            int b, tok;
            if (m < NPIX) {
                b = m / LWIN;
                int p = m - b * LWIN;
                int hh = p / 56, ww = p - hh * 56;
                tok = ((hh >> 3) * 7 + (ww >> 3)) * 64 + ((hh & 7) << 3) + (ww & 7);
            } else { b = m - NPIX; tok = LWIN; }
#pragma unroll
            for (int fn = 0; fn < 4; ++fn) {
                float val = acc[fm][fn][r] + bq[fn];
                size_t bh = (size_t)(b * NH + nhv[fn]);
                int d = dv[fn];
                if (part == 0) {
                    qh[(bh * NTOK + tok) * 32 + d] = (half_t)(val * SCALE_L2E);
                } else if (part == 1) {
                    if (tok < LWIN) kh[(bh * WINNUM + (tok >> 6)) * 2560 + (tok & 63) * 40 + d] = (half_t)val;
                    else            khcls[bh * 32 + d] = (half_t)val;
                } else {
                    vplain[(bh * NTOK + tok) * 32 + d] = (half_t)val;
                    if (tok < LWIN) vh[(bh * WINNUM + (tok >> 6)) * 2560 + d * 80 + (tok & 63)] = (half_t)val;
                }
            }
        }
    }
}

// ---------------------------------------------------------------------------
// win_attn: 512 threads = 8 waves. Wave (wq,wk) owns 16 queries x 32 keys;
// fixed-bias softmax makes (o,l) pure sums, so the two key-halves merge once
// at the end via LDS. Blocks [1568,1824) compute cls-query partials.
// ---------------------------------------------------------------------------
__global__ __launch_bounds__(512)
void win_attn(const half_t* __restrict__ qh, const half_t* __restrict__ kh,
              const half_t* __restrict__ khcls, const half_t* __restrict__ vh,
              const half_t* __restrict__ vplain, const int* __restrict__ mask,
              half_t* __restrict__ tg, float* __restrict__ clspart)
{
    const int id = blockIdx.x;
    const int tid = threadIdx.x;
    __shared__ __align__(16) int4 KV[2][640];       // K: [64][40] sh, V: [32][80] sh
    __shared__ __align__(16) short Plds[4][16 * 72];
    const int lane = tid & 63, wv = tid >> 6;

    if (id >= 1568) {
        // ---------------- cls partial block ----------------
        const int cid = id - 1568;       // 0..255
        const int bh = cid >> 3;
        const int chunk = cid & 7;
        const int wstart = chunk * 6;
        const int nw = (chunk < 7) ? 6 : 7;
        const int nkeys = nw * 64;

        float q[32];
        {
            const half_t* qp = qh + ((size_t)bh * NTOK + LWIN) * 32;
#pragma unroll
            for (int d = 0; d < 32; ++d) q[d] = (float)qp[d];
        }
        float l = 0.f, o[32];
#pragma unroll
        for (int d = 0; d < 32; ++d) o[d] = 0.f;

        const half_t* kwb = kh + (size_t)bh * (WINNUM * 2560) + wstart * 2560;
        const half_t* vb  = vplain + ((size_t)bh * NTOK + wstart * 64) * 32;

        if (tid < nkeys) {
            const half_t* kp = kwb + (tid >> 6) * 2560 + (tid & 63) * 40;
            float s = 0.f;
#pragma unroll
            for (int c8 = 0; c8 < 4; ++c8) {
                half8 kv = *(const half8*)(kp + c8 * 8);
#pragma unroll
                for (int j = 0; j < 8; ++j) s += q[c8 * 8 + j] * (float)kv[j];
            }
            float pp = exp2f(s - SM_BIAS);
            l += pp;
            const half_t* vp = vb + (size_t)tid * 32;
#pragma unroll
            for (int c8 = 0; c8 < 4; ++c8) {
                half8 vvv = *(const half8*)(vp + c8 * 8);
#pragma unroll
                for (int j = 0; j < 8; ++j) o[c8 * 8 + j] += pp * (float)vvv[j];
            }
        }
        if (chunk == 7 && tid == 0) {    // cls key
            const half_t* kp = khcls + bh * 32;
            float s = 0.f;
#pragma unroll
            for (int d = 0; d < 32; ++d) s += q[d] * (float)kp[d];
            float pp = exp2f(s - SM_BIAS);
            l += pp;
            const half_t* vp = vplain + ((size_t)bh * NTOK + LWIN) * 32;
#pragma unroll
            for (int d = 0; d < 32; ++d) o[d] += pp * (float)vp[d];
        }
#pragma unroll
        for (int off = 1; off < 64; off <<= 1) {
            l += __shfl_xor(l, off);
#pragma unroll
            for (int d = 0; d < 32; ++d) o[d] += __shfl_xor(o[d], off);
        }
        float* red = (float*)&KV[0][0];
        if (lane == 0) {
#pragma unroll
            for (int d = 0; d < 32; ++d) red[wv * 33 + d] = o[d];
            red[wv * 33 + 32] = l;
        }
        __syncthreads();
        if (tid < 33) {
            float s = 0.f;
#pragma unroll
            for (int wq = 0; wq < 8; ++wq) s += red[wq * 33 + tid];
            clspart[(bh * 8 + chunk) * 33 + tid] = s;
        }
        return;
    }

    // ---------------- window-attention block ----------------
    const int sw = (id & 7) * 196 + (id >> 3);   // XCD-chunked swizzle
    const int wi = sw % 49;
    const int bh = sw / 49;
    const int b = bh >> 3, nh = bh & 7;

    const int wq = wv & 3, wk = wv >> 2;
    const int g = lane >> 4, qi = lane & 15;
    const int qrow = wi * 64 + wq * 16 + qi;

    half8 aq = *(const half8*)(qh + ((size_t)bh * NTOK + qrow) * 32 + g * 8);

    float lacc = 0.f;
    f32x4 acc[2] = {{0.f,0.f,0.f,0.f},{0.f,0.f,0.f,0.f}};

    const int* mrow = mask + (b * WINNUM + wi) * WINNUM;
    int mv = (lane < WINNUM) ? mrow[lane] : 0;
    unsigned long long rem = __ballot(mv != 0);

    const int4* kwin = (const int4*)(kh + (size_t)bh * (WINNUM * 2560));
    const int4* vwin = (const int4*)(vh + (size_t)bh * (WINNUM * 2560));

    int4 r0, r1;
    auto issue = [&](int wj) {
        r0 = (tid < 320) ? kwin[wj * 320 + tid] : vwin[wj * 320 + tid - 320];
        if (tid < 128) r1 = vwin[wj * 320 + 192 + tid];
    };
    auto commit = [&](int bu) {
        KV[bu][tid] = r0;
        if (tid < 128) KV[bu][512 + tid] = r1;
    };

    int buf = 0;
    if (rem) { issue(__builtin_ctzll(rem)); commit(0); }
    __syncthreads();

    while (rem) {
        rem &= rem - 1;
        if (rem) issue(__builtin_ctzll(rem));   // next window's loads in flight

        const short* Kb = (const short*)&KV[buf][0];
        const short* Vb = (const short*)&KV[buf][320];

        // S^T: 2 tiles (keys wk*32 .. wk*32+31) for query column qi
        f32x4 st[2];
        __builtin_amdgcn_s_setprio(1);
#pragma unroll
        for (int t = 0; t < 2; ++t) {
            half8 ak = *(const half8*)&Kb[((2 * wk + t) * 16 + qi) * 40 + g * 8];
            st[t] = __builtin_amdgcn_mfma_f32_16x16x32_f16(ak, aq, (f32x4){0.f,0.f,0.f,0.f}, 0, 0, 0);
        }
        __builtin_amdgcn_s_setprio(0);
        float p[2][4];
#pragma unroll
        for (int t = 0; t < 2; ++t)
#pragma unroll
            for (int r = 0; r < 4; ++r) {
                p[t][r] = exp2f(st[t][r] - SM_BIAS);
                lacc += p[t][r];
            }
        // P -> LDS fp16 (own half only)
        {
            short* pw = &Plds[wq][qi * 72];
#pragma unroll
            for (int t = 0; t < 2; ++t)
#pragma unroll
                for (int r2 = 0; r2 < 2; ++r2)
                    *(unsigned*)&pw[(2 * wk + t) * 16 + g * 4 + r2 * 2] = pack2(p[t][2 * r2], p[t][2 * r2 + 1]);
        }
        // O^T += V^T . P^T  over own 32 keys
        __builtin_amdgcn_s_setprio(1);
        {
            half8 bp = *(const half8*)&Plds[wq][qi * 72 + wk * 32 + g * 8];
#pragma unroll
            for (int h2 = 0; h2 < 2; ++h2) {
                half8 av = *(const half8*)&Vb[(h2 * 16 + qi) * 80 + wk * 32 + g * 8];
                acc[h2] = __builtin_amdgcn_mfma_f32_16x16x32_f16(av, bp, acc[h2], 0, 0, 0);
            }
        }
        __builtin_amdgcn_s_setprio(0);

        if (rem) commit(buf ^ 1);
        __syncthreads();
        buf ^= 1;
    }

    // reduce l across g groups (own half)
    lacc += __shfl_xor(lacc, 16);
    lacc += __shfl_xor(lacc, 32);

    // merge the two key-halves via LDS (Plds dead now; 8704B <= 9216B)
    __syncthreads();
    float* comb = (float*)Plds;
    if (wk == 1) {
#pragma unroll
        for (int h2 = 0; h2 < 2; ++h2)
#pragma unroll
            for (int r = 0; r < 4; ++r)
                comb[wq * 544 + (h2 * 16 + g * 4 + r) * 16 + qi] = acc[h2][r];
        if (g == 0) comb[wq * 544 + 512 + qi] = lacc;
    }
    __syncthreads();
    if (wk == 0) {
#pragma unroll
        for (int h2 = 0; h2 < 2; ++h2)
#pragma unroll
            for (int r = 0; r < 4; ++r)
                acc[h2][r] += comb[wq * 544 + (h2 * 16 + g * 4 + r) * 16 + qi];
        float l = lacc + comb[wq * 544 + 512 + qi];

        // cls key (fp32 scalar, same bias)
        float kcls[8], vcls[2][4];
#pragma unroll
        for (int j = 0; j < 8; ++j) kcls[j] = (float)khcls[bh * 32 + g * 8 + j];
        {
            const half_t* vcb = vplain + ((size_t)bh * NTOK + LWIN) * 32;
#pragma unroll
            for (int h2 = 0; h2 < 2; ++h2)
#pragma unroll
                for (int r = 0; r < 4; ++r) vcls[h2][r] = (float)vcb[h2 * 16 + g * 4 + r];
        }
        float sc = 0.f;
#pragma unroll
        for (int j = 0; j < 8; ++j) sc += (float)aq[j] * kcls[j];
        sc += __shfl_xor(sc, 16);
        sc += __shfl_xor(sc, 32);
        float pc = exp2f(sc - SM_BIAS);
        l += pc;
#pragma unroll
        for (int h2 = 0; h2 < 2; ++h2)
#pragma unroll
            for (int r = 0; r < 4; ++r) acc[h2][r] += pc * vcls[h2][r];

        // write O to t[pix][nh*32 + d], d = 16*h2 + 4*g + r
        float inv = 1.f / l;
        int kk = wq * 16 + qi;
        int hh = (wi / 7) * 8 + (kk >> 3);
        int ww = (wi % 7) * 8 + (kk & 7);
        size_t pix = (size_t)b * LWIN + hh * 56 + ww;
        half_t* tp = tg + pix * 256 + nh * 32;
#pragma unroll
        for (int h2 = 0; h2 < 2; ++h2) {
            half4 hv;
#pragma unroll
            for (int r = 0; r < 4; ++r) hv[r] = (half_t)(acc[h2][r] * inv);
            *(half4*)(tp + h2 * 16 + g * 4) = hv;
        }
    }
}

// ---------------------------------------------------------------------------
// lepe_add: t[pix][c..c+7] += depthwise3x3(v) + lepe_b. Block 1568
// normalizes cls partials into th cls rows.
// ---------------------------------------------------------------------------
__global__ __launch_bounds__(256)
void lepe_add(const half_t* __restrict__ vplain, const float* __restrict__ lk,
              const float* __restrict__ lb, const float* __restrict__ clspart,
              half_t* __restrict__ tg)
{
    if (blockIdx.x == 1568) {
        const int c = threadIdx.x;
        const int nh = c >> 5, d = c & 31;
#pragma unroll
        for (int b = 0; b < 4; ++b) {
            int bh = b * NH + nh;
            float os = 0.f, ls = 0.f;
#pragma unroll
            for (int ch = 0; ch < 8; ++ch) {
                os += clspart[(bh * 8 + ch) * 33 + d];
                ls += clspart[(bh * 8 + ch) * 33 + 32];
            }
            tg[(size_t)(NPIX + b) * 256 + c] = (half_t)(os / ls);
        }
        return;
    }
    const int gidx = blockIdx.x * 256 + threadIdx.x;
    const int pix = gidx >> 5, cg = gidx & 31;
    const int c0 = cg * 8;
    const int b = pix / LWIN, p = pix - b * LWIN;
    const int hh = p / 56, ww = p - hh * 56;
    const int nh = c0 >> 5, d0 = c0 & 31;
    const half_t* vb = vplain + (size_t)(b * NH + nh) * NTOK * 32 + d0;

    float s[8];
#pragma unroll
    for (int j = 0; j < 8; ++j) s[j] = lb[c0 + j];
#pragma unroll
    for (int dh = -1; dh <= 1; ++dh) {
        int hn = hh + dh;
        if (hn < 0 || hn >= 56) continue;
#pragma unroll
        for (int dw = -1; dw <= 1; ++dw) {
            int wn = ww + dw;
            if (wn < 0 || wn >= 56) continue;
            int tok = ((hn >> 3) * 7 + (wn >> 3)) * 64 + ((hn & 7) << 3) + (wn & 7);
            half8 vvv = *(const half8*)(vb + (size_t)tok * 32);
            const float* kk = lk + ((dh + 1) * 3 + (dw + 1)) * 256 + c0;
#pragma unroll
            for (int j = 0; j < 8; ++j) s[j] += (float)vvv[j] * kk[j];
        }
    }
    half_t* tp = tg + (size_t)pix * 256 + c0;
    half8 cur = *(const half8*)tp;
    half8 outv;
#pragma unroll
    for (int j = 0; j < 8; ++j) outv[j] = (half_t)((float)cur[j] + s[j]);
    *(half8*)tp = outv;
}

// ---------------------------------------------------------------------------
// out_gemm: out = t @ Wo + bo (fp16 MFMA, fp32 out), reg-staged buffers.
// ---------------------------------------------------------------------------
__global__ __launch_bounds__(256)
void out_gemm(const half_t* __restrict__ th, const half_t* __restrict__ Bt,
              const float* __restrict__ bo, float* __restrict__ out)
{
    __shared__ __align__(16) short As[2][128 * 40];
    __shared__ __align__(16) short Bs[2][128 * 40];
    const int m0 = blockIdx.y * 128, n0 = blockIdx.x * 128;
    const int tid = threadIdx.x;
    const int lane = tid & 63, wv = tid >> 6;
    const int wm = wv >> 1, wn = wv & 1;
    const int qi = lane & 15, g = lane >> 4;
    f32x4 acc[4][4] = {};

    int4 ra[2], rb[2];
    auto issue = [&](int k0) {
#pragma unroll
        for (int i = 0; i < 2; ++i) {
            int ch = tid + 256 * i;
            int row = ch >> 2, kc = (ch & 3) * 8;
            int m = m0 + row;
            ra[i] = (m < MROWS) ? *(const int4*)(th + (size_t)m * 256 + k0 + kc)
                                : make_int4(0, 0, 0, 0);
            rb[i] = *(const int4*)(Bt + (size_t)(n0 + row) * 256 + k0 + kc);
        }
    };
    auto commit = [&](int bu) {
#pragma unroll
        for (int i = 0; i < 2; ++i) {
            int ch = tid + 256 * i;
            int row = ch >> 2, kc = (ch & 3) * 8;
            *(int4*)&As[bu][row * 40 + kc] = ra[i];
            *(int4*)&Bs[bu][row * 40 + kc] = rb[i];
        }
    };

    issue(0); commit(0);
    __syncthreads();
    int buf = 0;
    for (int s = 0; s < 8; ++s) {
        if (s < 7) issue((s + 1) * 32);
        half8 af[4], bf[4];
#pragma unroll
        for (int f = 0; f < 4; ++f) {
            af[f] = *(const half8*)&As[buf][(wm * 64 + f * 16 + qi) * 40 + g * 8];
            bf[f] = *(const half8*)&Bs[buf][(wn * 64 + f * 16 + qi) * 40 + g * 8];
        }
#pragma unroll
        for (int fm = 0; fm < 4; ++fm)
#pragma unroll
            for (int fn = 0; fn < 4; ++fn)
                acc[fm][fn] = __builtin_amdgcn_mfma_f32_16x16x32_f16(af[fm], bf[fn], acc[fm][fn], 0, 0, 0);
        if (s < 7) commit(buf ^ 1);
        __syncthreads();
        buf ^= 1;
    }

    float bov[4];
    int nn[4];
#pragma unroll
    for (int fn = 0; fn < 4; ++fn) {
        nn[fn] = n0 + wn * 64 + fn * 16 + qi;
        bov[fn] = bo[nn[fn]];
    }
#pragma unroll
    for (int fm = 0; fm < 4; ++fm)
#pragma unroll
        for (int r = 0; r < 4; ++r) {
            int m = m0 + wm * 64 + fm * 16 + g * 4 + r;
            if (m >= MROWS) continue;
#pragma unroll
            for (int fn = 0; fn < 4; ++fn)
                out[(size_t)m * 256 + nn[fn]] = acc[fm][fn][r] + bov[fn];
        }
}

// ---------------------------------------------------------------------------
extern "C" void kernel_launch(void* const* d_in, const int* in_sizes, int n_in,
                              void* d_out, int out_size, void* d_ws, size_t ws_size,
                              hipStream_t stream)
{
    const float* x    = (const float*)d_in[0];
    const float* cls  = (const float*)d_in[1];
    const int*   mask = (const int*)d_in[2];
    const float* Wqkv = (const float*)d_in[5];
    const float* bqkv = (const float*)d_in[6];
    const float* Wo   = (const float*)d_in[7];
    const float* bo   = (const float*)d_in[8];
    const float* lk   = (const float*)d_in[9];
    const float* lb   = (const float*)d_in[10];
    float* out = (float*)d_out;

    char* w = (char*)d_ws;
    half_t* xh     = (half_t*)w;  w += 6424576;   // 12548*256*2
    half_t* qh     = (half_t*)w;  w += 6424576;   // 32*3137*32*2
    half_t* kh     = (half_t*)w;  w += 8028160;   // 32*49*2560*2
    half_t* khcls  = (half_t*)w;  w += 2048;      // 32*32*2
    half_t* vh     = (half_t*)w;  w += 8028160;   // 32*49*2560*2
    half_t* vplain = (half_t*)w;  w += 6424576;
    half_t* Wqkvt  = (half_t*)w;  w += 393216;    // 768*256*2
    half_t* Wot    = (half_t*)w;  w += 131072;    // 256*256*2
    half_t* th     = (half_t*)w;  w += 6424576;   // 12548*256*2
    float*  clspart= (float*)w;   w += 33792;     // 32*8*33*4

    prep<<<1600, 256, 0, stream>>>(x, cls, Wqkv, Wo, xh, Wqkvt, Wot);
    qkv_gemm<<<dim3(6, 99), 256, 0, stream>>>(xh, Wqkvt, bqkv, qh, kh, khcls, vh, vplain);
    win_attn<<<1824, 512, 0, stream>>>(qh, kh, khcls, vh, vplain, mask, th, clspart);
    lepe_add<<<1569, 256, 0, stream>>>(vplain, lk, lb, clspart, th);
    out_gemm<<<dim3(2, 99), 256, 0, stream>>>(th, Wot, bo, out);
}

// Round 8
// 122.127 us; speedup vs baseline: 1.0691x; 1.0691x over previous
//
#include <hip/hip_runtime.h>
#include <math.h>

#define B_      4
#define NH      8
#define HD      32
#define WINNUM  49
#define LWIN    3136
#define NTOK    3137
#define NPIX    12544     // B * 56 * 56
#define MROWS   12548     // NPIX + 4 cls rows
// 256^-0.5 * log2(e): scores land in exp2 domain
#define SCALE_L2E 0.09016844005556021f
#define SM_BIAS   4.0f    // fixed softmax bias (cancels in normalization)

typedef _Float16 half_t;
using half8 = __attribute__((ext_vector_type(8))) half_t;
using half4 = __attribute__((ext_vector_type(4))) half_t;
using f32x4 = __attribute__((ext_vector_type(4))) float;

__device__ __forceinline__ unsigned pack2(float a, float b) {
    auto h = __builtin_amdgcn_cvt_pkrtz(a, b);   // __fp16 ext_vector(2)
    return __builtin_bit_cast(unsigned, h);
}
__device__ __forceinline__ half8 as_h8(int4 v) {
    return __builtin_bit_cast(half8, v);
}

// ---------------------------------------------------------------------------
// prep: xh = fp16([x;cls]) (12548,256); Wqkvt (768,256) and Wot (256,256)
// transposed fp16 (row = output col, k contiguous).
// ---------------------------------------------------------------------------
__global__ __launch_bounds__(256)
void prep(const float* __restrict__ x, const float* __restrict__ cls,
          const float* __restrict__ Wqkv, const float* __restrict__ Wo,
          half_t* __restrict__ xh, half_t* __restrict__ Wqkvt, half_t* __restrict__ Wot)
{
    const int idx = blockIdx.x * 256 + threadIdx.x;
    const int stride = gridDim.x * 256;
    for (int i = idx; i < MROWS * 256; i += stride) {
        int row = i >> 8, c = i & 255;
        float v = (row < NPIX) ? x[i] : cls[(row - NPIX) * 256 + c];
        xh[i] = (half_t)v;
    }
    for (int i = idx; i < 768 * 256; i += stride) {
        int n = i >> 8, k = i & 255;
        Wqkvt[i] = (half_t)Wqkv[k * 768 + n];
    }
    for (int i = idx; i < 256 * 256; i += stride) {
        int n = i >> 8, k = i & 255;
        Wot[i] = (half_t)Wo[k * 256 + n];
    }
}

// ---------------------------------------------------------------------------
// qkv_gemm: C = xh @ Wqkv + bqkv via fp16 MFMA, 128x128 tile, 4 waves.
// Reg-staged double buffer. Epilogue scatters q/k/v to attention layouts.
// ---------------------------------------------------------------------------
__global__ __launch_bounds__(256)
void qkv_gemm(const half_t* __restrict__ xh, const half_t* __restrict__ Bt,
              const float* __restrict__ bqkv,
              half_t* __restrict__ qh, half_t* __restrict__ kh,
              half_t* __restrict__ khcls, half_t* __restrict__ vh,
              half_t* __restrict__ vplain)
{
    __shared__ __align__(16) short As[2][128 * 40];
    __shared__ __align__(16) short Bs[2][128 * 40];
    const int m0 = blockIdx.y * 128, n0 = blockIdx.x * 128;
    const int tid = threadIdx.x;
    const int lane = tid & 63, wv = tid >> 6;
    const int wm = wv >> 1, wn = wv & 1;
    const int qi = lane & 15, g = lane >> 4;
    f32x4 acc[4][4] = {};

    int4 ra[2], rb[2];
    auto issue = [&](int k0) {
#pragma unroll
        for (int i = 0; i < 2; ++i) {
            int ch = tid + 256 * i;
            int row = ch >> 2, kc = (ch & 3) * 8;
            int m = m0 + row;
            ra[i] = (m < MROWS) ? *(const int4*)(xh + (size_t)m * 256 + k0 + kc)
                                : make_int4(0, 0, 0, 0);
            rb[i] = *(const int4*)(Bt + (size_t)(n0 + row) * 256 + k0 + kc);
        }
    };
    auto commit = [&](int bu) {
#pragma unroll
        for (int i = 0; i < 2; ++i) {
            int ch = tid + 256 * i;
            int row = ch >> 2, kc = (ch & 3) * 8;
            *(int4*)&As[bu][row * 40 + kc] = ra[i];
            *(int4*)&Bs[bu][row * 40 + kc] = rb[i];
        }
    };

    issue(0); commit(0);
    __syncthreads();
    int buf = 0;
    for (int s = 0; s < 8; ++s) {
        if (s < 7) issue((s + 1) * 32);
        half8 af[4], bf[4];
#pragma unroll
        for (int f = 0; f < 4; ++f) {
            af[f] = *(const half8*)&As[buf][(wm * 64 + f * 16 + qi) * 40 + g * 8];
            bf[f] = *(const half8*)&Bs[buf][(wn * 64 + f * 16 + qi) * 40 + g * 8];
        }
#pragma unroll
        for (int fm = 0; fm < 4; ++fm)
#pragma unroll
            for (int fn = 0; fn < 4; ++fn)
                acc[fm][fn] = __builtin_amdgcn_mfma_f32_16x16x32_f16(af[fm], bf[fn], acc[fm][fn], 0, 0, 0);
        if (s < 7) commit(buf ^ 1);
        __syncthreads();
        buf ^= 1;
    }

    const int part = n0 >> 8;
    int nhv[4], dv[4];
    float bq[4];
#pragma unroll
    for (int fn = 0; fn < 4; ++fn) {
        int n = n0 + wn * 64 + fn * 16 + qi;
        bq[fn] = bqkv[n];
        int c = n & 255;
        nhv[fn] = c >> 5; dv[fn] = c & 31;
    }
#pragma unroll
    for (int fm = 0; fm < 4; ++fm) {
#pragma unroll
        for (int r = 0; r < 4; ++r) {
            int m = m0 + wm * 64 + fm * 16 + g * 4 + r;
            if (m >= MROWS) continue;
            int b, tok;
            if (m < NPIX) {
                b = m / LWIN;
                int p = m - b * LWIN;
                int hh = p / 56, ww = p - hh * 56;
                tok = ((hh >> 3) * 7 + (ww >> 3)) * 64 + ((hh & 7) << 3) + (ww & 7);
            } else { b = m - NPIX; tok = LWIN; }
#pragma unroll
            for (int fn = 0; fn < 4; ++fn) {
                float val = acc[fm][fn][r] + bq[fn];
                size_t bh = (size_t)(b * NH + nhv[fn]);
                int d = dv[fn];
                if (part == 0) {
                    qh[(bh * NTOK + tok) * 32 + d] = (half_t)(val * SCALE_L2E);
                } else if (part == 1) {
                    if (tok < LWIN) kh[(bh * WINNUM + (tok >> 6)) * 2560 + (tok & 63) * 40 + d] = (half_t)val;
                    else            khcls[bh * 32 + d] = (half_t)val;
                } else {
                    vplain[(bh * NTOK + tok) * 32 + d] = (half_t)val;
                    if (tok < LWIN) vh[(bh * WINNUM + (tok >> 6)) * 2560 + d * 80 + (tok & 63)] = (half_t)val;
                }
            }
        }
    }
}

// ---------------------------------------------------------------------------
// win_attn: BARRIER-FREE window attention. 256 threads = 4 independent waves;
// wave wv owns queries wv*16..+15 and iterates its row's active windows,
// loading K/V MFMA fragments global->register directly (16B/lane each).
// P redistribution goes through per-wave LDS (intra-wave lgkm ordering only,
// no __syncthreads anywhere). Blocks [1568,1824) = cls-query partials.
// ---------------------------------------------------------------------------
__global__ __launch_bounds__(256)
void win_attn(const half_t* __restrict__ qh, const half_t* __restrict__ kh,
              const half_t* __restrict__ khcls, const half_t* __restrict__ vh,
              const half_t* __restrict__ vplain, const int* __restrict__ mask,
              half_t* __restrict__ tg, float* __restrict__ clspart)
{
    const int id = blockIdx.x;
    const int tid = threadIdx.x;
    __shared__ __align__(16) short Plds[4][16 * 72];   // 9216 B
    __shared__ float redc[4 * 33];                     // cls reduce scratch
    const int lane = tid & 63, wv = tid >> 6;

    if (id >= 1568) {
        // ---------------- cls partial block ----------------
        const int cid = id - 1568;       // 0..255
        const int bh = cid >> 3;
        const int chunk = cid & 7;
        const int wstart = chunk * 6;
        const int nw = (chunk < 7) ? 6 : 7;
        const int nkeys = nw * 64;

        float q[32];
        {
            const half_t* qp = qh + ((size_t)bh * NTOK + LWIN) * 32;
#pragma unroll
            for (int d = 0; d < 32; ++d) q[d] = (float)qp[d];
        }
        float l = 0.f, o[32];
#pragma unroll
        for (int d = 0; d < 32; ++d) o[d] = 0.f;

        const half_t* kwb = kh + (size_t)bh * (WINNUM * 2560) + wstart * 2560;
        const half_t* vb  = vplain + ((size_t)bh * NTOK + wstart * 64) * 32;

        for (int kk = tid; kk < nkeys; kk += 256) {
            const half_t* kp = kwb + (kk >> 6) * 2560 + (kk & 63) * 40;
            float s = 0.f;
#pragma unroll
            for (int c8 = 0; c8 < 4; ++c8) {
                half8 kv = *(const half8*)(kp + c8 * 8);
#pragma unroll
                for (int j = 0; j < 8; ++j) s += q[c8 * 8 + j] * (float)kv[j];
            }
            float pp = exp2f(s - SM_BIAS);
            l += pp;
            const half_t* vp = vb + (size_t)kk * 32;
#pragma unroll
            for (int c8 = 0; c8 < 4; ++c8) {
                half8 vvv = *(const half8*)(vp + c8 * 8);
#pragma unroll
                for (int j = 0; j < 8; ++j) o[c8 * 8 + j] += pp * (float)vvv[j];
            }
        }
        if (chunk == 7 && tid == 0) {    // cls key
            const half_t* kp = khcls + bh * 32;
            float s = 0.f;
#pragma unroll
            for (int d = 0; d < 32; ++d) s += q[d] * (float)kp[d];
            float pp = exp2f(s - SM_BIAS);
            l += pp;
            const half_t* vp = vplain + ((size_t)bh * NTOK + LWIN) * 32;
#pragma unroll
            for (int d = 0; d < 32; ++d) o[d] += pp * (float)vp[d];
        }
#pragma unroll
        for (int off = 1; off < 64; off <<= 1) {
            l += __shfl_xor(l, off);
#pragma unroll
            for (int d = 0; d < 32; ++d) o[d] += __shfl_xor(o[d], off);
        }
        if (lane == 0) {
#pragma unroll
            for (int d = 0; d < 32; ++d) redc[wv * 33 + d] = o[d];
            redc[wv * 33 + 32] = l;
        }
        __syncthreads();
        if (tid < 33) {
            float s = redc[tid] + redc[33 + tid] + redc[66 + tid] + redc[99 + tid];
            clspart[(bh * 8 + chunk) * 33 + tid] = s;
        }
        return;
    }

    // ---------------- window-attention block (no barriers) ----------------
    const int sw = (id & 7) * 196 + (id >> 3);   // XCD-chunked swizzle
    const int wi = sw % 49;
    const int bh = sw / 49;
    const int b = bh >> 3, nh = bh & 7;

    const int g = lane >> 4, qi = lane & 15;
    const int qrow = wi * 64 + wv * 16 + qi;

    half8 aq = *(const half8*)(qh + ((size_t)bh * NTOK + qrow) * 32 + g * 8);

    float lacc = 0.f;
    f32x4 acc[2] = {{0.f,0.f,0.f,0.f},{0.f,0.f,0.f,0.f}};

    const int* mrow = mask + (b * WINNUM + wi) * WINNUM;
    int mv = (lane < WINNUM) ? mrow[lane] : 0;
    unsigned long long rem = __ballot(mv != 0);

    const half_t* kwin = kh + (size_t)bh * (WINNUM * 2560);
    const half_t* vwin = vh + (size_t)bh * (WINNUM * 2560);
    const int koff = qi * 40 + g * 8;   // + t*640 per K tile
    const int voff = qi * 80 + g * 8;   // + h2*1280 + s2*32

    short* pw = &Plds[wv][qi * 72];
    const short* prd = &Plds[wv][qi * 72 + g * 8];

    while (rem) {
        const int wj = __builtin_ctzll(rem);
        rem &= rem - 1;
        const half_t* kb = kwin + wj * 2560 + koff;
        const half_t* vb = vwin + wj * 2560 + voff;
        // K fragments (4 tiles), then V fragments — all 8 loads in flight
        int4 kf0 = *(const int4*)(kb);
        int4 kf1 = *(const int4*)(kb + 640);
        int4 kf2 = *(const int4*)(kb + 1280);
        int4 kf3 = *(const int4*)(kb + 1920);
        int4 vf00 = *(const int4*)(vb);
        int4 vf01 = *(const int4*)(vb + 32);
        int4 vf10 = *(const int4*)(vb + 1280);
        int4 vf11 = *(const int4*)(vb + 1312);

        // S^T = mfma(K, Q): lane (qi,g) holds keys 16t+4g+r for query qi
        f32x4 st[4];
        __builtin_amdgcn_s_setprio(1);
        st[0] = __builtin_amdgcn_mfma_f32_16x16x32_f16(as_h8(kf0), aq, (f32x4){0.f,0.f,0.f,0.f}, 0, 0, 0);
        st[1] = __builtin_amdgcn_mfma_f32_16x16x32_f16(as_h8(kf1), aq, (f32x4){0.f,0.f,0.f,0.f}, 0, 0, 0);
        st[2] = __builtin_amdgcn_mfma_f32_16x16x32_f16(as_h8(kf2), aq, (f32x4){0.f,0.f,0.f,0.f}, 0, 0, 0);
        st[3] = __builtin_amdgcn_mfma_f32_16x16x32_f16(as_h8(kf3), aq, (f32x4){0.f,0.f,0.f,0.f}, 0, 0, 0);
        __builtin_amdgcn_s_setprio(0);

        // fixed-bias softmax + pack to per-wave LDS (keys 16t+4g..+3)
#pragma unroll
        for (int t = 0; t < 4; ++t) {
            float p0 = exp2f(st[t][0] - SM_BIAS);
            float p1 = exp2f(st[t][1] - SM_BIAS);
            float p2 = exp2f(st[t][2] - SM_BIAS);
            float p3 = exp2f(st[t][3] - SM_BIAS);
            lacc += (p0 + p1) + (p2 + p3);
            uint2 pk = make_uint2(pack2(p0, p1), pack2(p2, p3));
            *(uint2*)&pw[t * 16 + 4 * g] = pk;
        }
        // P^T fragments (keys s2*32+g*8..+7 for query qi) and PV
        half8 bp0 = *(const half8*)(prd);
        half8 bp1 = *(const half8*)(prd + 32);
        __builtin_amdgcn_s_setprio(1);
        acc[0] = __builtin_amdgcn_mfma_f32_16x16x32_f16(as_h8(vf00), bp0, acc[0], 0, 0, 0);
        acc[1] = __builtin_amdgcn_mfma_f32_16x16x32_f16(as_h8(vf10), bp0, acc[1], 0, 0, 0);
        acc[0] = __builtin_amdgcn_mfma_f32_16x16x32_f16(as_h8(vf01), bp1, acc[0], 0, 0, 0);
        acc[1] = __builtin_amdgcn_mfma_f32_16x16x32_f16(as_h8(vf11), bp1, acc[1], 0, 0, 0);
        __builtin_amdgcn_s_setprio(0);
    }

    // reduce l across the 4 g-groups
    lacc += __shfl_xor(lacc, 16);
    lacc += __shfl_xor(lacc, 32);

    // cls key (fp32 scalar, same bias)
    float kcls[8], vcls[2][4];
#pragma unroll
    for (int j = 0; j < 8; ++j) kcls[j] = (float)khcls[bh * 32 + g * 8 + j];
    {
        const half_t* vcb = vplain + ((size_t)bh * NTOK + LWIN) * 32;
#pragma unroll
        for (int h2 = 0; h2 < 2; ++h2)
#pragma unroll
            for (int r = 0; r < 4; ++r) vcls[h2][r] = (float)vcb[h2 * 16 + g * 4 + r];
    }
    float sc = 0.f;
#pragma unroll
    for (int j = 0; j < 8; ++j) sc += (float)aq[j] * kcls[j];
    sc += __shfl_xor(sc, 16);
    sc += __shfl_xor(sc, 32);
    float pc = exp2f(sc - SM_BIAS);
    float l = lacc + pc;
#pragma unroll
    for (int h2 = 0; h2 < 2; ++h2)
#pragma unroll
        for (int r = 0; r < 4; ++r) acc[h2][r] += pc * vcls[h2][r];

    // write O to t[pix][nh*32 + d], d = 16*h2 + 4*g + r
    {
        float inv = 1.f / l;
        int kk = wv * 16 + qi;
        int hh = (wi / 7) * 8 + (kk >> 3);
        int ww = (wi % 7) * 8 + (kk & 7);
        size_t pix = (size_t)b * LWIN + hh * 56 + ww;
        half_t* tp = tg + pix * 256 + nh * 32;
#pragma unroll
        for (int h2 = 0; h2 < 2; ++h2) {
            half4 hv;
#pragma unroll
            for (int r = 0; r < 4; ++r) hv[r] = (half_t)(acc[h2][r] * inv);
            *(half4*)(tp + h2 * 16 + g * 4) = hv;
        }
    }
}

// ---------------------------------------------------------------------------
// lepe_add: t[pix][c..c+7] += depthwise3x3(v) + lepe_b. Block 1568
// normalizes cls partials into th cls rows.
// ---------------------------------------------------------------------------
__global__ __launch_bounds__(256)
void lepe_add(const half_t* __restrict__ vplain, const float* __restrict__ lk,
              const float* __restrict__ lb, const float* __restrict__ clspart,
              half_t* __restrict__ tg)
{
    if (blockIdx.x == 1568) {
        const int c = threadIdx.x;
        const int nh = c >> 5, d = c & 31;
#pragma unroll
        for (int b = 0; b < 4; ++b) {
            int bh = b * NH + nh;
            float os = 0.f, ls = 0.f;
#pragma unroll
            for (int ch = 0; ch < 8; ++ch) {
                os += clspart[(bh * 8 + ch) * 33 + d];
                ls += clspart[(bh * 8 + ch) * 33 + 32];
            }
            tg[(size_t)(NPIX + b) * 256 + c] = (half_t)(os / ls);
        }
        return;
    }
    const int gidx = blockIdx.x * 256 + threadIdx.x;
    const int pix = gidx >> 5, cg = gidx & 31;
    const int c0 = cg * 8;
    const int b = pix / LWIN, p = pix - b * LWIN;
    const int hh = p / 56, ww = p - hh * 56;
    const int nh = c0 >> 5, d0 = c0 & 31;
    const half_t* vb = vplain + (size_t)(b * NH + nh) * NTOK * 32 + d0;

    float s[8];
#pragma unroll
    for (int j = 0; j < 8; ++j) s[j] = lb[c0 + j];
#pragma unroll
    for (int dh = -1; dh <= 1; ++dh) {
        int hn = hh + dh;
        if (hn < 0 || hn >= 56) continue;
#pragma unroll
        for (int dw = -1; dw <= 1; ++dw) {
            int wn = ww + dw;
            if (wn < 0 || wn >= 56) continue;
            int tok = ((hn >> 3) * 7 + (wn >> 3)) * 64 + ((hn & 7) << 3) + (wn & 7);
            half8 vvv = *(const half8*)(vb + (size_t)tok * 32);
            const float* kk = lk + ((dh + 1) * 3 + (dw + 1)) * 256 + c0;
#pragma unroll
            for (int j = 0; j < 8; ++j) s[j] += (float)vvv[j] * kk[j];
        }
    }
    half_t* tp = tg + (size_t)pix * 256 + c0;
    half8 cur = *(const half8*)tp;
    half8 outv;
#pragma unroll
    for (int j = 0; j < 8; ++j) outv[j] = (half_t)((float)cur[j] + s[j]);
    *(half8*)tp = outv;
}

// ---------------------------------------------------------------------------
// out_gemm: out = t @ Wo + bo (fp16 MFMA, fp32 out), reg-staged buffers.
// ---------------------------------------------------------------------------
__global__ __launch_bounds__(256)
void out_gemm(const half_t* __restrict__ th, const half_t* __restrict__ Bt,
              const float* __restrict__ bo, float* __restrict__ out)
{
    __shared__ __align__(16) short As[2][128 * 40];
    __shared__ __align__(16) short Bs[2][128 * 40];
    const int m0 = blockIdx.y * 128, n0 = blockIdx.x * 128;
    const int tid = threadIdx.x;
    const int lane = tid & 63, wv = tid >> 6;
    const int wm = wv >> 1, wn = wv & 1;
    const int qi = lane & 15, g = lane >> 4;
    f32x4 acc[4][4] = {};

    int4 ra[2], rb[2];
    auto issue = [&](int k0) {
#pragma unroll
        for (int i = 0; i < 2; ++i) {
            int ch = tid + 256 * i;
            int row = ch >> 2, kc = (ch & 3) * 8;
            int m = m0 + row;
            ra[i] = (m < MROWS) ? *(const int4*)(th + (size_t)m * 256 + k0 + kc)
                                : make_int4(0, 0, 0, 0);
            rb[i] = *(const int4*)(Bt + (size_t)(n0 + row) * 256 + k0 + kc);
        }
    };
    auto commit = [&](int bu) {
#pragma unroll
        for (int i = 0; i < 2; ++i) {
            int ch = tid + 256 * i;
            int row = ch >> 2, kc = (ch & 3) * 8;
            *(int4*)&As[bu][row * 40 + kc] = ra[i];
            *(int4*)&Bs[bu][row * 40 + kc] = rb[i];
        }
    };

    issue(0); commit(0);
    __syncthreads();
    int buf = 0;
    for (int s = 0; s < 8; ++s) {
        if (s < 7) issue((s + 1) * 32);
        half8 af[4], bf[4];
#pragma unroll
        for (int f = 0; f < 4; ++f) {
            af[f] = *(const half8*)&As[buf][(wm * 64 + f * 16 + qi) * 40 + g * 8];
            bf[f] = *(const half8*)&Bs[buf][(wn * 64 + f * 16 + qi) * 40 + g * 8];
        }
#pragma unroll
        for (int fm = 0; fm < 4; ++fm)
#pragma unroll
            for (int fn = 0; fn < 4; ++fn)
                acc[fm][fn] = __builtin_amdgcn_mfma_f32_16x16x32_f16(af[fm], bf[fn], acc[fm][fn], 0, 0, 0);
        if (s < 7) commit(buf ^ 1);
        __syncthreads();
        buf ^= 1;
    }

    float bov[4];
    int nn[4];
#pragma unroll
    for (int fn = 0; fn < 4; ++fn) {
        nn[fn] = n0 + wn * 64 + fn * 16 + qi;
        bov[fn] = bo[nn[fn]];
    }
#pragma unroll
    for (int fm = 0; fm < 4; ++fm)
#pragma unroll
        for (int r = 0; r < 4; ++r) {
            int m = m0 + wm * 64 + fm * 16 + g * 4 + r;
            if (m >= MROWS) continue;
#pragma unroll
            for (int fn = 0; fn < 4; ++fn)
                out[(size_t)m * 256 + nn[fn]] = acc[fm][fn][r] + bov[fn];
        }
}

// ---------------------------------------------------------------------------
extern "C" void kernel_launch(void* const* d_in, const int* in_sizes, int n_in,
                              void* d_out, int out_size, void* d_ws, size_t ws_size,
                              hipStream_t stream)
{
    const float* x    = (const float*)d_in[0];
    const float* cls  = (const float*)d_in[1];
    const int*   mask = (const int*)d_in[2];
    const float* Wqkv = (const float*)d_in[5];
    const float* bqkv = (const float*)d_in[6];
    const float* Wo   = (const float*)d_in[7];
    const float* bo   = (const float*)d_in[8];
    const float* lk   = (const float*)d_in[9];
    const float* lb   = (const float*)d_in[10];
    float* out = (float*)d_out;

    char* w = (char*)d_ws;
    half_t* xh     = (half_t*)w;  w += 6424576;   // 12548*256*2
    half_t* qh     = (half_t*)w;  w += 6424576;   // 32*3137*32*2
    half_t* kh     = (half_t*)w;  w += 8028160;   // 32*49*2560*2
    half_t* khcls  = (half_t*)w;  w += 2048;      // 32*32*2
    half_t* vh     = (half_t*)w;  w += 8028160;   // 32*49*2560*2
    half_t* vplain = (half_t*)w;  w += 6424576;
    half_t* Wqkvt  = (half_t*)w;  w += 393216;    // 768*256*2
    half_t* Wot    = (half_t*)w;  w += 131072;    // 256*256*2
    half_t* th     = (half_t*)w;  w += 6424576;   // 12548*256*2
    float*  clspart= (float*)w;   w += 33792;     // 32*8*33*4

    prep<<<1600, 256, 0, stream>>>(x, cls, Wqkv, Wo, xh, Wqkvt, Wot);
    qkv_gemm<<<dim3(6, 99), 256, 0, stream>>>(xh, Wqkvt, bqkv, qh, kh, khcls, vh, vplain);
    win_attn<<<1824, 256, 0, stream>>>(qh, kh, khcls, vh, vplain, mask, th, clspart);
    lepe_add<<<1569, 256, 0, stream>>>(vplain, lk, lb, clspart, th);
    out_gemm<<<dim3(2, 99), 256, 0, stream>>>(th, Wot, bo, out);
}